// Round 6
// baseline (237.497 us; speedup 1.0000x reference)
//
#include <hip/hip_runtime.h>
#include <math.h>

// Problem: X[16384,64] fp32, W[8192,64] fp32 -> argmin_c ||x-w_c||^2 (int32)
#define EMB    64
#define NTOK   8192
#define NQ     16384
#define TPB    256
#define CBLK   32                 // codeword blocks: each = 4 waves x 64 codewords = 256
#define QBLK   32                 // query splits
#define NBLK   (CBLK * QBLK)      // 1024 blocks = 4/CU
#define QPB    (NQ / QBLK)        // 512 queries per block
#define NTILE  (QPB / 16)         // 32 16-query MFMA tiles per wave

typedef _Float16 half8 __attribute__((ext_vector_type(8)));
typedef float    f32x4 __attribute__((ext_vector_type(4)));

// ---------------------------------------------------------------------------
// Prep (full): split X -> fp16 hi/lo (x ~= xh + xl), init best[] + counter.
// 131072 threads, one 8-elem segment each. Moves the O(N) conversion out of
// the O(N*C) hot loop.
// ---------------------------------------------------------------------------
__global__ void prep_full(const float* __restrict__ X,
                          _Float16* __restrict__ Xh, _Float16* __restrict__ Xl,
                          unsigned long long* __restrict__ best,
                          unsigned* __restrict__ counter) {
    int u = blockIdx.x * blockDim.x + threadIdx.x;   // 0 .. NQ*8-1
    if (u == 0) *counter = 0u;
    if (u < NQ) best[u] = ~0ULL;
    int q = u >> 3, seg = u & 7;
    const float* xp = X + (size_t)q * EMB + seg * 8;
    float4 v0 = *(const float4*)xp;
    float4 v1 = *(const float4*)(xp + 4);
    float xv[8] = {v0.x, v0.y, v0.z, v0.w, v1.x, v1.y, v1.z, v1.w};
    half8 h, l;
#pragma unroll
    for (int j = 0; j < 8; ++j) {
        _Float16 hh = (_Float16)xv[j];
        h[j] = hh;
        l[j] = (_Float16)(xv[j] - (float)hh);
    }
    *(half8*)(Xh + (size_t)q * EMB + seg * 8) = h;
    *(half8*)(Xl + (size_t)q * EMB + seg * 8) = l;
}

// Prep (minimal, fallback when ws can't hold Xh/Xl): init best[] + counter.
__global__ void prep_min(unsigned long long* __restrict__ best,
                         unsigned* __restrict__ counter) {
    int u = blockIdx.x * blockDim.x + threadIdx.x;
    if (u == 0) *counter = 0u;
    if (u < NQ) best[u] = ~0ULL;
}

// ---------------------------------------------------------------------------
// Main: zero-LDS, zero-barrier MFMA distance + argmin.
// Each wave owns 64 codewords: A = split(-2w) lives in 64 VGPRs, converted
// ONCE. Queries stream through as B (half8 loads from Xh/Xl; fallback
// converts X fp32 in-kernel). 3-term split product (Al*Bh + Ah*Bl + Ah*Bh;
// the l*l term is ~2^-22 rel, dropped — absmax 0 in R3/R4/R5).
// MFMA 16x16x32_f16 (measured m89/m91): A[m=lane&15][k=(lane>>4)*8+j],
// C col=lane&15, row=(lane>>4)*4+reg. C-init = ||w_row||^2 so acc IS the
// distance. Argmin: in-lane min over 16 rows -> shfl_xor(16,32) across the
// row-holding lane groups -> packed u64 atomicMin per query (monotone float
// encode, idx in low bits -> equal dist = lowest index = first-wins).
// No __syncthreads in the hot loop: waves are fully independent.
// NOTE: launch_bounds must NOT request 4 waves/EU (R4: snaps VGPR budget to
// 64 and spills the fragment set). (256,3) -> 168-VGPR budget, fits ~140.
// ---------------------------------------------------------------------------
template <bool PRE>
__global__ __launch_bounds__(TPB, 3) void vq_main(
    const float* __restrict__ X,
    const _Float16* __restrict__ Xh, const _Float16* __restrict__ Xl,
    const float* __restrict__ W,
    unsigned long long* __restrict__ best,
    unsigned* __restrict__ counter,
    int* __restrict__ out)
{
    __shared__ int lastFlag;

    const int t    = threadIdx.x;
    const int lane = t & 63;
    const int wid  = t >> 6;        // 0..3
    const int l15  = lane & 15;
    const int lq   = lane >> 4;     // 0..3

    const int cwb = blockIdx.x * 256 + wid * 64;   // this wave's 64 codewords
    const int qsb = blockIdx.y * QPB;

    // --- one-time: A fragments = fp16 split of (-2 * W) for 64 codewords ---
    half8 Ah[4][2], Al[4][2];
#pragma unroll
    for (int ct = 0; ct < 4; ++ct) {
#pragma unroll
        for (int kb = 0; kb < 2; ++kb) {
            const float* wp = W + (size_t)(cwb + ct * 16 + l15) * EMB + kb * 32 + lq * 8;
            float4 v0 = *(const float4*)wp;
            float4 v1 = *(const float4*)(wp + 4);
            float wv[8] = {v0.x, v0.y, v0.z, v0.w, v1.x, v1.y, v1.z, v1.w};
            half8 h, l;
#pragma unroll
            for (int j = 0; j < 8; ++j) {
                float m2 = -2.f * wv[j];
                _Float16 hh = (_Float16)m2;
                h[j] = hh;
                l[j] = (_Float16)(m2 - (float)hh);
            }
            Ah[ct][kb] = h;
            Al[ct][kb] = l;
        }
    }

    // --- one-time: ||w||^2 per codeword; redistribute to C-row layout ---
    float ynown = 0.f;
    {
        const float4* wp = (const float4*)(W + (size_t)(cwb + lane) * EMB);
#pragma unroll
        for (int i = 0; i < 16; ++i) {
            float4 v = wp[i];
            ynown = fmaf(v.x, v.x, ynown);
            ynown = fmaf(v.y, v.y, ynown);
            ynown = fmaf(v.z, v.z, ynown);
            ynown = fmaf(v.w, v.w, ynown);
        }
    }
    float ynreg[4][4];   // ynreg[ct][r] = ||w_{ct*16 + lq*4 + r}||^2
#pragma unroll
    for (int ct = 0; ct < 4; ++ct)
#pragma unroll
        for (int r = 0; r < 4; ++r)
            ynreg[ct][r] = __shfl(ynown, ct * 16 + lq * 4 + r, 64);

    // --- hot loop: stream queries, no barriers ---
    for (int qt = 0; qt < NTILE; ++qt) {
        const int qb = qsb + qt * 16;

        half8 Bh[2], Bl[2];
        if constexpr (PRE) {
#pragma unroll
            for (int kb = 0; kb < 2; ++kb) {
                Bh[kb] = *(const half8*)(Xh + (size_t)(qb + l15) * EMB + kb * 32 + lq * 8);
                Bl[kb] = *(const half8*)(Xl + (size_t)(qb + l15) * EMB + kb * 32 + lq * 8);
            }
        } else {
#pragma unroll
            for (int kb = 0; kb < 2; ++kb) {
                const float* xp = X + (size_t)(qb + l15) * EMB + kb * 32 + lq * 8;
                float4 v0 = *(const float4*)xp;
                float4 v1 = *(const float4*)(xp + 4);
                float xv[8] = {v0.x, v0.y, v0.z, v0.w, v1.x, v1.y, v1.z, v1.w};
                half8 h, l;
#pragma unroll
                for (int j = 0; j < 8; ++j) {
                    _Float16 hh = (_Float16)xv[j];
                    h[j] = hh;
                    l[j] = (_Float16)(xv[j] - (float)hh);
                }
                Bh[kb] = h;
                Bl[kb] = l;
            }
        }

        f32x4 acc[4];
#pragma unroll
        for (int ct = 0; ct < 4; ++ct) {
            f32x4 a = {ynreg[ct][0], ynreg[ct][1], ynreg[ct][2], ynreg[ct][3]};
            a = __builtin_amdgcn_mfma_f32_16x16x32_f16(Al[ct][0], Bh[0], a, 0, 0, 0);
            a = __builtin_amdgcn_mfma_f32_16x16x32_f16(Ah[ct][0], Bl[0], a, 0, 0, 0);
            a = __builtin_amdgcn_mfma_f32_16x16x32_f16(Ah[ct][0], Bh[0], a, 0, 0, 0);
            a = __builtin_amdgcn_mfma_f32_16x16x32_f16(Al[ct][1], Bh[1], a, 0, 0, 0);
            a = __builtin_amdgcn_mfma_f32_16x16x32_f16(Ah[ct][1], Bl[1], a, 0, 0, 0);
            a = __builtin_amdgcn_mfma_f32_16x16x32_f16(Ah[ct][1], Bh[1], a, 0, 0, 0);
            acc[ct] = a;
        }

        // --- argmin over this wave's 64 codewords for 16 queries ---
        float bv = INFINITY;
        int   bi = 0;
#pragma unroll
        for (int ct = 0; ct < 4; ++ct) {
#pragma unroll
            for (int r = 0; r < 4; ++r) {
                float v = acc[ct][r];
                int  ci = cwb + ct * 16 + lq * 4 + r;   // ascending -> strict < = first-wins
                if (v < bv) { bv = v; bi = ci; }
            }
        }
#pragma unroll
        for (int m = 16; m <= 32; m <<= 1) {
            float ov = __shfl_xor(bv, m, 64);
            int   oi = __shfl_xor(bi, m, 64);
            if (ov < bv || (ov == bv && oi < bi)) { bv = ov; bi = oi; }
        }
        if (lane < 16) {
            unsigned ub = __float_as_uint(bv);
            ub = (ub & 0x80000000u) ? ~ub : (ub | 0x80000000u);
            unsigned long long packed = ((unsigned long long)ub << 32) | (unsigned)bi;
            atomicMin(best + qb + lane, packed);
        }
    }

    // --- last-done block extracts indices (saves a kernel launch; R5-proven) ---
    __threadfence();
    if (t == 0) {
        unsigned done = __hip_atomic_fetch_add(counter, 1u, __ATOMIC_ACQ_REL,
                                               __HIP_MEMORY_SCOPE_AGENT);
        lastFlag = (done == NBLK - 1) ? 1 : 0;
    }
    __syncthreads();
    if (lastFlag) {
        for (int q = t; q < NQ; q += TPB) {
            unsigned long long p = __hip_atomic_load(best + q, __ATOMIC_RELAXED,
                                                     __HIP_MEMORY_SCOPE_AGENT);
            out[q] = (int)(p & 0xFFFFFFFFu);
        }
    }
}

// ---------------------------------------------------------------------------
extern "C" void kernel_launch(void* const* d_in, const int* in_sizes, int n_in,
                              void* d_out, int out_size, void* d_ws, size_t ws_size,
                              hipStream_t stream) {
    const float* X = (const float*)d_in[0];   // [16384, 64]
    const float* W = (const float*)d_in[1];   // [8192, 64]
    int* out = (int*)d_out;

    // ws layout: best (128 KB) | counter (64 B) | Xh (2 MB) | Xl (2 MB)
    unsigned long long* best = (unsigned long long*)d_ws;
    unsigned* counter = (unsigned*)(best + NQ);
    _Float16* Xh = (_Float16*)((char*)d_ws + NQ * 8 + 64);
    _Float16* Xl = Xh + (size_t)NQ * EMB;
    const size_t need = (size_t)NQ * 8 + 64 + (size_t)NQ * EMB * 2 * 2;

    dim3 grid(CBLK, QBLK);
    if (ws_size >= need) {
        prep_full<<<(NQ * 8) / TPB, TPB, 0, stream>>>(X, Xh, Xl, best, counter);
        vq_main<true><<<grid, TPB, 0, stream>>>(X, Xh, Xl, W, best, counter, out);
    } else {
        prep_min<<<NQ / TPB, TPB, 0, stream>>>(best, counter);
        vq_main<false><<<grid, TPB, 0, stream>>>(X, Xh, Xl, W, best, counter, out);
    }
}

// Round 7
// 222.615 us; speedup vs baseline: 1.0669x; 1.0669x over previous
//
#include <hip/hip_runtime.h>
#include <math.h>

// Problem: X[16384,64] fp32, W[8192,64] fp32 -> argmin_c ||x-w_c||^2 (int32)
#define EMB    64
#define NTOK   8192
#define NQ     16384
#define TPB    256
#define CBLK   32                 // codeword blocks: each = 4 waves x 64 codewords = 256
#define QBLK   32                 // query splits
#define NBLK   (CBLK * QBLK)      // 1024 blocks = 4/CU
#define QPB    (NQ / QBLK)        // 512 queries per block
#define NTILE  (QPB / 16)         // 32 16-query MFMA tiles per wave

typedef _Float16 half8 __attribute__((ext_vector_type(8)));
typedef float    f32x4 __attribute__((ext_vector_type(4)));

// ---------------------------------------------------------------------------
// Prep (full): split X -> fp16 hi/lo (x ~= xh + xl), init best[] + counter.
// ---------------------------------------------------------------------------
__global__ void prep_full(const float* __restrict__ X,
                          _Float16* __restrict__ Xh, _Float16* __restrict__ Xl,
                          unsigned long long* __restrict__ best,
                          unsigned* __restrict__ counter) {
    int u = blockIdx.x * blockDim.x + threadIdx.x;   // 0 .. NQ*8-1
    if (u == 0) *counter = 0u;
    if (u < NQ) best[u] = ~0ULL;
    int q = u >> 3, seg = u & 7;
    const float* xp = X + (size_t)q * EMB + seg * 8;
    float4 v0 = *(const float4*)xp;
    float4 v1 = *(const float4*)(xp + 4);
    float xv[8] = {v0.x, v0.y, v0.z, v0.w, v1.x, v1.y, v1.z, v1.w};
    half8 h, l;
#pragma unroll
    for (int j = 0; j < 8; ++j) {
        _Float16 hh = (_Float16)xv[j];
        h[j] = hh;
        l[j] = (_Float16)(xv[j] - (float)hh);
    }
    *(half8*)(Xh + (size_t)q * EMB + seg * 8) = h;
    *(half8*)(Xl + (size_t)q * EMB + seg * 8) = l;
}

// Prep (minimal fallback): init best[] + counter only.
__global__ void prep_min(unsigned long long* __restrict__ best,
                         unsigned* __restrict__ counter) {
    int u = blockIdx.x * blockDim.x + threadIdx.x;
    if (u == 0) *counter = 0u;
    if (u < NQ) best[u] = ~0ULL;
}

// ---------------------------------------------------------------------------
// Main: zero-barrier-hot-loop MFMA distance + argmin.
// Each wave owns 64 codewords: A = split(-2w) in 64 VGPRs, converted ONCE.
// Queries stream as B (half8 loads, 1-deep prefetch). 3-term split product
// (Al*Bh + Ah*Bl + Ah*Bh; l*l term ~2^-22 rel, dropped — absmax 0 R3..R6).
// MFMA 16x16x32_f16 (measured m89/m91): A[m=lane&15][k=(lane>>4)*8+j],
// C col=lane&15, row=(lane>>4)*4+reg. C-init = ||w_row||^2 -> acc IS dist.
//
// R6 LESSON: do NOT put atomics in the hot loop — vmcnt is issue-ordered, so
// a per-tile atomicMin forces every following load-wait to drain a device-
// scope atomic round trip (185 us, MfmaUtil 11%). Partials now go to LDS
// (lgkm pipe, off the vmcnt chain); one block-combine + fire-and-forget
// atomic burst after the loop.
// NOTE: launch_bounds must NOT request 4 waves/EU (R4: snaps VGPR budget to
// 64 and spills the fragment set).
// ---------------------------------------------------------------------------
template <bool PRE>
__global__ __launch_bounds__(TPB, 3) void vq_main(
    const float* __restrict__ X,
    const _Float16* __restrict__ Xh, const _Float16* __restrict__ Xl,
    const float* __restrict__ W,
    unsigned long long* __restrict__ best,
    unsigned* __restrict__ counter,
    int* __restrict__ out)
{
    __shared__ unsigned long long part[4][NTILE][16];   // 16 KB partials
    __shared__ int lastFlag;

    const int t    = threadIdx.x;
    const int lane = t & 63;
    const int wid  = t >> 6;        // 0..3
    const int l15  = lane & 15;
    const int lq   = lane >> 4;     // 0..3

    const int cwb = blockIdx.x * 256 + wid * 64;   // this wave's 64 codewords
    const int qsb = blockIdx.y * QPB;

    // --- one-time: A fragments = fp16 split of (-2 * W) for 64 codewords ---
    half8 Ah[4][2], Al[4][2];
#pragma unroll
    for (int ct = 0; ct < 4; ++ct) {
#pragma unroll
        for (int kb = 0; kb < 2; ++kb) {
            const float* wp = W + (size_t)(cwb + ct * 16 + l15) * EMB + kb * 32 + lq * 8;
            float4 v0 = *(const float4*)wp;
            float4 v1 = *(const float4*)(wp + 4);
            float wv[8] = {v0.x, v0.y, v0.z, v0.w, v1.x, v1.y, v1.z, v1.w};
            half8 h, l;
#pragma unroll
            for (int j = 0; j < 8; ++j) {
                float m2 = -2.f * wv[j];
                _Float16 hh = (_Float16)m2;
                h[j] = hh;
                l[j] = (_Float16)(m2 - (float)hh);
            }
            Ah[ct][kb] = h;
            Al[ct][kb] = l;
        }
    }

    // --- one-time: ||w||^2 per codeword; redistribute to C-row layout ---
    float ynown = 0.f;
    {
        const float4* wp = (const float4*)(W + (size_t)(cwb + lane) * EMB);
#pragma unroll
        for (int i = 0; i < 16; ++i) {
            float4 v = wp[i];
            ynown = fmaf(v.x, v.x, ynown);
            ynown = fmaf(v.y, v.y, ynown);
            ynown = fmaf(v.z, v.z, ynown);
            ynown = fmaf(v.w, v.w, ynown);
        }
    }
    float ynreg[4][4];   // ynreg[ct][r] = ||w_{ct*16 + lq*4 + r}||^2
#pragma unroll
    for (int ct = 0; ct < 4; ++ct)
#pragma unroll
        for (int r = 0; r < 4; ++r)
            ynreg[ct][r] = __shfl(ynown, ct * 16 + lq * 4 + r, 64);

    // --- B loader (registers only; PRE -> half8 loads, else fp32+convert) ---
    auto loadB = [&](int qb, half8 (&Bh)[2], half8 (&Bl)[2]) {
        if constexpr (PRE) {
#pragma unroll
            for (int kb = 0; kb < 2; ++kb) {
                Bh[kb] = *(const half8*)(Xh + (size_t)(qb + l15) * EMB + kb * 32 + lq * 8);
                Bl[kb] = *(const half8*)(Xl + (size_t)(qb + l15) * EMB + kb * 32 + lq * 8);
            }
        } else {
#pragma unroll
            for (int kb = 0; kb < 2; ++kb) {
                const float* xp = X + (size_t)(qb + l15) * EMB + kb * 32 + lq * 8;
                float4 v0 = *(const float4*)xp;
                float4 v1 = *(const float4*)(xp + 4);
                float xv[8] = {v0.x, v0.y, v0.z, v0.w, v1.x, v1.y, v1.z, v1.w};
                half8 h, l;
#pragma unroll
                for (int j = 0; j < 8; ++j) {
                    _Float16 hh = (_Float16)xv[j];
                    h[j] = hh;
                    l[j] = (_Float16)(xv[j] - (float)hh);
                }
                Bh[kb] = h;
                Bl[kb] = l;
            }
        }
    };

    // --- hot loop: stream queries; LDS partials; NO atomics, NO barriers ---
    half8 Bh[2], Bl[2], nBh[2], nBl[2];
    loadB(qsb, Bh, Bl);
#pragma unroll 2
    for (int qt = 0; qt < NTILE; ++qt) {
        if (qt + 1 < NTILE) loadB(qsb + (qt + 1) * 16, nBh, nBl);

        f32x4 acc[4];
#pragma unroll
        for (int ct = 0; ct < 4; ++ct) {
            f32x4 a = {ynreg[ct][0], ynreg[ct][1], ynreg[ct][2], ynreg[ct][3]};
            a = __builtin_amdgcn_mfma_f32_16x16x32_f16(Al[ct][0], Bh[0], a, 0, 0, 0);
            a = __builtin_amdgcn_mfma_f32_16x16x32_f16(Ah[ct][0], Bl[0], a, 0, 0, 0);
            a = __builtin_amdgcn_mfma_f32_16x16x32_f16(Ah[ct][0], Bh[0], a, 0, 0, 0);
            a = __builtin_amdgcn_mfma_f32_16x16x32_f16(Al[ct][1], Bh[1], a, 0, 0, 0);
            a = __builtin_amdgcn_mfma_f32_16x16x32_f16(Ah[ct][1], Bl[1], a, 0, 0, 0);
            a = __builtin_amdgcn_mfma_f32_16x16x32_f16(Ah[ct][1], Bh[1], a, 0, 0, 0);
            acc[ct] = a;
        }

        // argmin over this wave's 64 codewords for 16 queries
        float bv = INFINITY;
        int   bi = 0;
#pragma unroll
        for (int ct = 0; ct < 4; ++ct) {
#pragma unroll
            for (int r = 0; r < 4; ++r) {
                float v = acc[ct][r];
                int  ci = cwb + ct * 16 + lq * 4 + r;   // ascending -> strict < = first-wins
                if (v < bv) { bv = v; bi = ci; }
            }
        }
#pragma unroll
        for (int m = 16; m <= 32; m <<= 1) {
            float ov = __shfl_xor(bv, m, 64);
            int   oi = __shfl_xor(bi, m, 64);
            if (ov < bv || (ov == bv && oi < bi)) { bv = ov; bi = oi; }
        }
        // monotone float encode, idx in low bits -> u64 min == (dist, idx) lex min
        unsigned ub = __float_as_uint(bv);
        ub = (ub & 0x80000000u) ? ~ub : (ub | 0x80000000u);
        unsigned long long packed = ((unsigned long long)ub << 32) | (unsigned)bi;
        if (lane < 16) part[wid][qt][lane] = packed;   // ds_write: off the vmcnt chain

        Bh[0] = nBh[0]; Bh[1] = nBh[1];
        Bl[0] = nBl[0]; Bl[1] = nBl[1];
    }

    // --- block combine (4 waves) + fire-and-forget atomic burst ---
    __syncthreads();
#pragma unroll
    for (int k = 0; k < QPB / TPB; ++k) {
        int q = t + k * TPB;                  // 0..511
        int qt = q >> 4, li = q & 15;
        unsigned long long b = part[0][qt][li];
#pragma unroll
        for (int w = 1; w < 4; ++w) {
            unsigned long long p = part[w][qt][li];
            if (p < b) b = p;
        }
        atomicMin(best + qsb + q, b);         // nothing depends on this until the fence
    }

    // --- last-done block extracts indices ---
    __threadfence();
    if (t == 0) {
        unsigned done = __hip_atomic_fetch_add(counter, 1u, __ATOMIC_ACQ_REL,
                                               __HIP_MEMORY_SCOPE_AGENT);
        lastFlag = (done == NBLK - 1) ? 1 : 0;
    }
    __syncthreads();
    if (lastFlag) {
        for (int q = t; q < NQ; q += TPB) {
            unsigned long long p = __hip_atomic_load(best + q, __ATOMIC_RELAXED,
                                                     __HIP_MEMORY_SCOPE_AGENT);
            out[q] = (int)(p & 0xFFFFFFFFu);
        }
    }
}

// ---------------------------------------------------------------------------
extern "C" void kernel_launch(void* const* d_in, const int* in_sizes, int n_in,
                              void* d_out, int out_size, void* d_ws, size_t ws_size,
                              hipStream_t stream) {
    const float* X = (const float*)d_in[0];   // [16384, 64]
    const float* W = (const float*)d_in[1];   // [8192, 64]
    int* out = (int*)d_out;

    // ws layout: best (128 KB) | counter (64 B) | Xh (2 MB) | Xl (2 MB)
    unsigned long long* best = (unsigned long long*)d_ws;
    unsigned* counter = (unsigned*)(best + NQ);
    _Float16* Xh = (_Float16*)((char*)d_ws + NQ * 8 + 64);
    _Float16* Xl = Xh + (size_t)NQ * EMB;
    const size_t need = (size_t)NQ * 8 + 64 + (size_t)NQ * EMB * 2 * 2;

    dim3 grid(CBLK, QBLK);
    if (ws_size >= need) {
        prep_full<<<(NQ * 8) / TPB, TPB, 0, stream>>>(X, Xh, Xl, best, counter);
        vq_main<true><<<grid, TPB, 0, stream>>>(X, Xh, Xl, W, best, counter, out);
    } else {
        prep_min<<<NQ / TPB, TPB, 0, stream>>>(best, counter);
        vq_main<false><<<grid, TPB, 0, stream>>>(X, Xh, Xl, W, best, counter, out);
    }
}

// Round 8
// 156.316 us; speedup vs baseline: 1.5193x; 1.4241x over previous
//
#include <hip/hip_runtime.h>
#include <math.h>

// Problem: X[16384,64] fp32, W[8192,64] fp32 -> argmin_c ||x-w_c||^2 (int32)
#define EMB     64
#define NTOK    8192
#define NQ      16384
#define TPB     256
#define NSPLIT  4                  // R3-proven best; 512 blocks = 2/CU, one resident round
#define CRANGE  (NTOK / NSPLIT)    // 2048 codewords per block
#define NTILES  (CRANGE / 128)     // 16 staged tiles per block
#define BQ      128                // query rows per block
#define NBLK    ((NQ / BQ) * NSPLIT)   // 512

typedef _Float16 half8 __attribute__((ext_vector_type(8)));
typedef float    f32x4 __attribute__((ext_vector_type(4)));

// global_load_lds width=16: lds dest = wave-uniform base + lane*16 (m97 recipe)
__device__ __forceinline__ void gload_lds16(const void* g, void* l) {
    __builtin_amdgcn_global_load_lds(
        (const __attribute__((address_space(1))) void*)g,
        (__attribute__((address_space(3))) void*)l, 16, 0, 0);
}

// ---------------------------------------------------------------------------
// Prep (fused, one dispatch): per codeword c —
//   ynorm[c] = ||w_c||^2  (fp32)
//   split(-2*w_c) -> fp16 hi/lo, written PRE-SWIZZLED into MFMA-B-fragment-
//   major order:  WS[tile=c>>7][frag][lane][8]  where frag = sub*2+kb for hi,
//   16+sub*2+kb for lo;  sub=(c>>4)&7, lane=lq*16+(c&15), k=kb*32+lq*8+j.
//   This makes the main loop's staging a pure lane-linear global_load_lds.
// Also inits best[] (packed u64 argmin table) + counter.
// ---------------------------------------------------------------------------
__global__ void prep_kernel(const float* __restrict__ W,
                            _Float16* __restrict__ WS,
                            float* __restrict__ ynorm,
                            unsigned long long* __restrict__ best,
                            unsigned* __restrict__ counter) {
    int c = blockIdx.x * blockDim.x + threadIdx.x;   // 0..8191
    if (c >= NTOK) return;
    if (c == 0) *counter = 0u;
    best[c] = ~0ULL;                 // 16384 entries, 8192 threads -> 2 each
    best[c + NTOK] = ~0ULL;

    const float* wp = W + (size_t)c * EMB;
    const int T   = c >> 7;
    const int sub = (c >> 4) & 7;
    const int cl  = c & 15;
    float s = 0.f;
#pragma unroll
    for (int seg = 0; seg < 8; ++seg) {              // k = seg*8 .. seg*8+7
        const int kb = seg >> 2, lq = seg & 3;
        float4 v0 = *(const float4*)(wp + seg * 8);
        float4 v1 = *(const float4*)(wp + seg * 8 + 4);
        float xv[8] = {v0.x, v0.y, v0.z, v0.w, v1.x, v1.y, v1.z, v1.w};
        half8 h, l;
#pragma unroll
        for (int j = 0; j < 8; ++j) {
            s = fmaf(xv[j], xv[j], s);
            float m2 = -2.f * xv[j];
            _Float16 hh = (_Float16)m2;
            h[j] = hh;
            l[j] = (_Float16)(m2 - (float)hh);
        }
        const size_t slot = (size_t)(lq * 16 + cl) * 8;
        *(half8*)(WS + ((size_t)T * 32 + sub * 2 + kb)      * 512 + slot) = h;
        *(half8*)(WS + ((size_t)T * 32 + 16 + sub * 2 + kb) * 512 + slot) = l;
    }
    ynorm[c] = s;
}

// ---------------------------------------------------------------------------
// Main: R3 skeleton (proven best, 101 us) + m97 staging.
// Block: 4 waves = 2(q-half) x 2(c-half).  A = query fp16 hi/lo in registers
// (converted once).  Per 128-codeword tile: 8 global_load_lds(16B) per wave
// stage the 32 pre-swizzled 1KB B-fragments (hi+lo) -> zero staging VALU,
// zero VGPR round-trip; reads back as lane-linear conflict-free ds_read_b128.
// 3-term split product (al*bh + ah*bl + ah*bh, B=split(-2w); l*l ~2^-22,
// dropped — absmax 0 since R3).  C-init = ||w_col||^2 -> acc IS the distance.
// Epilogue: per-lane argmin -> shfl_xor over 16 col-lanes -> LDS combine of
// c-halves -> packed-u64 atomicMin (monotone encode, idx low bits = exact
// first-wins) -> last-done block extracts (fused, saves a dispatch).
// NOTE: launch_bounds must stay (256,3) — (256,4) snaps VGPR budget to 64
// and spills the fragment set (R4: 900 MB scratch traffic, 2x slower).
// ---------------------------------------------------------------------------
__global__ __launch_bounds__(TPB, 3) void vq_main(
    const float* __restrict__ X,
    const _Float16* __restrict__ WS,
    const float* __restrict__ ynorm,
    unsigned long long* __restrict__ best,
    unsigned* __restrict__ counter,
    int* __restrict__ out)
{
    __shared__ _Float16 F[32 * 512];       // 32 KB: 32 fragments x 64 lanes x 16B
    __shared__ float RedV[2][BQ];
    __shared__ int   RedI[2][BQ];
    __shared__ int   lastFlag;

    const int t    = threadIdx.x;
    const int lane = t & 63;
    const int wid  = t >> 6;       // 0..3
    const int wq   = wid & 1;      // q half
    const int wy   = wid >> 1;     // c half
    const int l15  = lane & 15;
    const int lq   = lane >> 4;

    const int qblk  = blockIdx.x * BQ;
    const int qbase = qblk + wq * 64;
    const int tile0 = blockIdx.y * NTILES;

    // --- one-time: A fragments = fp16 split of X rows ---
    half8 ah[4][2], al[4][2];
#pragma unroll
    for (int mt = 0; mt < 4; ++mt) {
#pragma unroll
        for (int kb = 0; kb < 2; ++kb) {
            const float* xp = X + (size_t)(qbase + mt * 16 + l15) * EMB + kb * 32 + lq * 8;
            float4 v0 = *(const float4*)xp;
            float4 v1 = *(const float4*)(xp + 4);
            float xv[8] = {v0.x, v0.y, v0.z, v0.w, v1.x, v1.y, v1.z, v1.w};
            half8 h, l;
#pragma unroll
            for (int j = 0; j < 8; ++j) {
                _Float16 hh = (_Float16)xv[j];
                h[j] = hh;
                l[j] = (_Float16)(xv[j] - (float)hh);
            }
            ah[mt][kb] = h;
            al[mt][kb] = l;
        }
    }

    float minv[4][4];
    int   mini[4][4];
#pragma unroll
    for (int mt = 0; mt < 4; ++mt)
#pragma unroll
        for (int r = 0; r < 4; ++r) { minv[mt][r] = INFINITY; mini[mt][r] = 0; }

    for (int tt = 0; tt < NTILES; ++tt) {
        const int T  = tile0 + tt;
        const int cb = T * 128;

        __syncthreads();   // previous-iter F reads done before overwrite
        // --- stage 32 KB tile: 8 global_load_lds(16B) per wave, no VALU ---
        {
            const _Float16* gs = WS + ((size_t)T * 32 + wid * 8) * 512 + lane * 8;
            char* ld = (char*)F + wid * 8 * 1024;
#pragma unroll
            for (int i = 0; i < 8; ++i)
                gload_lds16(gs + i * 512, ld + i * 1024);
        }
        float ynv[4];
#pragma unroll
        for (int ct = 0; ct < 4; ++ct)
            ynv[ct] = ynorm[cb + (wy * 4 + ct) * 16 + l15];
        __syncthreads();   // drains vmcnt incl. global_load_lds

#pragma unroll
        for (int ct = 0; ct < 4; ++ct) {
            const int sub = wy * 4 + ct;
            const half8 bh0 = *(const half8*)&F[(size_t)(sub * 2 + 0) * 512 + lane * 8];
            const half8 bh1 = *(const half8*)&F[(size_t)(sub * 2 + 1) * 512 + lane * 8];
            const half8 bl0 = *(const half8*)&F[(size_t)(16 + sub * 2 + 0) * 512 + lane * 8];
            const half8 bl1 = *(const half8*)&F[(size_t)(16 + sub * 2 + 1) * 512 + lane * 8];
            const f32x4 cinit = {ynv[ct], ynv[ct], ynv[ct], ynv[ct]};
            const int cidx = cb + sub * 16 + l15;
#pragma unroll
            for (int mt = 0; mt < 4; ++mt) {
                f32x4 a = cinit;
                a = __builtin_amdgcn_mfma_f32_16x16x32_f16(al[mt][0], bh0, a, 0, 0, 0);
                a = __builtin_amdgcn_mfma_f32_16x16x32_f16(ah[mt][0], bl0, a, 0, 0, 0);
                a = __builtin_amdgcn_mfma_f32_16x16x32_f16(ah[mt][0], bh0, a, 0, 0, 0);
                a = __builtin_amdgcn_mfma_f32_16x16x32_f16(al[mt][1], bh1, a, 0, 0, 0);
                a = __builtin_amdgcn_mfma_f32_16x16x32_f16(ah[mt][1], bl1, a, 0, 0, 0);
                a = __builtin_amdgcn_mfma_f32_16x16x32_f16(ah[mt][1], bh1, a, 0, 0, 0);
#pragma unroll
                for (int r = 0; r < 4; ++r)
                    if (a[r] < minv[mt][r]) { minv[mt][r] = a[r]; mini[mt][r] = cidx; }
            }
        }
    }

    // --- cross-lane: reduce over the 16 col-lanes ---
#pragma unroll
    for (int mt = 0; mt < 4; ++mt) {
#pragma unroll
        for (int r = 0; r < 4; ++r) {
            float v = minv[mt][r];
            int   i = mini[mt][r];
#pragma unroll
            for (int m = 1; m <= 8; m <<= 1) {
                float ov = __shfl_xor(v, m, 64);
                int   oi = __shfl_xor(i, m, 64);
                if (ov < v || (ov == v && oi < i)) { v = ov; i = oi; }
            }
            if (l15 == 0) {
                int qoff = wq * 64 + mt * 16 + lq * 4 + r;
                RedV[wy][qoff] = v;
                RedI[wy][qoff] = i;
            }
        }
    }
    __syncthreads();

    // --- combine c-halves; packed atomicMin (first-wins exact) ---
    if (t < BQ) {
        float v0 = RedV[0][t]; int i0 = RedI[0][t];
        float v1 = RedV[1][t]; int i1 = RedI[1][t];
        if (v1 < v0 || (v1 == v0 && i1 < i0)) { v0 = v1; i0 = i1; }
        unsigned ub = __float_as_uint(v0);
        ub = (ub & 0x80000000u) ? ~ub : (ub | 0x80000000u);
        unsigned long long packed = ((unsigned long long)ub << 32) | (unsigned)i0;
        atomicMin(best + qblk + t, packed);
    }

    // --- last-done block extracts indices ---
    __threadfence();
    if (t == 0) {
        unsigned done = __hip_atomic_fetch_add(counter, 1u, __ATOMIC_ACQ_REL,
                                               __HIP_MEMORY_SCOPE_AGENT);
        lastFlag = (done == NBLK - 1) ? 1 : 0;
    }
    __syncthreads();
    if (lastFlag) {
        for (int q = t; q < NQ; q += TPB) {
            unsigned long long p = __hip_atomic_load(best + q, __ATOMIC_RELAXED,
                                                     __HIP_MEMORY_SCOPE_AGENT);
            out[q] = (int)(p & 0xFFFFFFFFu);
        }
    }
}

// ---------------------------------------------------------------------------
extern "C" void kernel_launch(void* const* d_in, const int* in_sizes, int n_in,
                              void* d_out, int out_size, void* d_ws, size_t ws_size,
                              hipStream_t stream) {
    const float* X = (const float*)d_in[0];   // [16384, 64]
    const float* W = (const float*)d_in[1];   // [8192, 64]
    int* out = (int*)d_out;

    // ws: WS (2 MB, swizzled -2W hi/lo frags) | ynorm (32 KB) | best (128 KB) | counter
    _Float16* WS    = (_Float16*)d_ws;
    float*    ynorm = (float*)(WS + (size_t)NTOK * EMB * 2);
    unsigned long long* best = (unsigned long long*)(ynorm + NTOK);
    unsigned* counter = (unsigned*)(best + NQ);

    prep_kernel<<<NTOK / TPB, TPB, 0, stream>>>(W, WS, ynorm, best, counter);
    dim3 grid(NQ / BQ, NSPLIT);
    vq_main<<<grid, TPB, 0, stream>>>(X, WS, ynorm, best, counter, out);
}